// Round 16
// baseline (551.417 us; speedup 1.0000x reference)
//
#include <hip/hip_runtime.h>
#include <math.h>

#define HID 128
#define RBF 32
#define NL 6
#define BINS 4096
#define DMAXF 5.0f
#define INV_STEP (4096.0f / 5.0f)
#define GAMMAF 32.0f
#define CSPACE (4.0f / 31.0f)   // linspace(0,4,32) spacing
#define TM 32                   // rows per block

typedef _Float16 half8v __attribute__((ext_vector_type(8)));
typedef _Float16 half4v __attribute__((ext_vector_type(4)));
typedef float f32x4 __attribute__((ext_vector_type(4)));

// softplus(x)-0.5 via HW transcendentals (v_exp_f32/v_log_f32)
__device__ __forceinline__ float sspf(float x) {
    return fmaxf(x, 0.0f) + __logf(1.0f + __expf(-fabsf(x))) - 0.5f;
}

// ---------- one-time preprocessing ----------

#define SB 256
__global__ void k_scan1(const int* __restrict__ counts, int* __restrict__ pre,
                        int* __restrict__ bsums, int n) {
    __shared__ int s[SB];
    int tid = threadIdx.x;
    int g = blockIdx.x * SB + tid;
    int v = (g < n) ? counts[g] : 0;
    s[tid] = v;
    __syncthreads();
    for (int off = 1; off < SB; off <<= 1) {
        int t = (tid >= off) ? s[tid - off] : 0;
        __syncthreads();
        s[tid] += t;
        __syncthreads();
    }
    if (g < n) pre[g] = s[tid] - v;
    if (tid == SB - 1) bsums[blockIdx.x] = s[tid];
}

__global__ void k_scan2(int* __restrict__ bsums, int nb) {
    __shared__ int s[1024];
    int tid = threadIdx.x;
    int v = (tid < nb) ? bsums[tid] : 0;
    s[tid] = v;
    __syncthreads();
    for (int off = 1; off < 1024; off <<= 1) {
        int t = (tid >= off) ? s[tid - off] : 0;
        __syncthreads();
        s[tid] += t;
        __syncthreads();
    }
    if (tid < nb) bsums[tid] = s[tid] - v;
}

// exclusive-scan apply + front/back cursors (clamped edges fill from front,
// near edges from back -> runs of same type per CSR segment)
__global__ void k_scan3(const int* __restrict__ pre, const int* __restrict__ bsums,
                        const int* __restrict__ counts, int* __restrict__ row_ofs,
                        int* __restrict__ curF, int* __restrict__ curB,
                        float* __restrict__ invdeg, int n) {
    int g = blockIdx.x * SB + threadIdx.x;
    if (g >= n) return;
    int r = pre[g] + bsums[g >> 8];
    row_ofs[g] = r;
    curF[g] = r;
    curB[g] = r + counts[g];
    invdeg[g] = 1.0f / fmaxf((float)counts[g], 1.0f);
    if (g == n - 1) row_ofs[n] = r + counts[g];
}

__global__ void k_scatter(const int* __restrict__ ei, const float* __restrict__ pos,
                          int* __restrict__ curF, int* __restrict__ curB,
                          unsigned int* __restrict__ epk, int E_) {
    int e = blockIdx.x * blockDim.x + threadIdx.x;
    if (e >= E_) return;
    int i = ei[e], j = ei[E_ + e];
    float dx = pos[3 * i]     - pos[3 * j];
    float dy = pos[3 * i + 1] - pos[3 * j + 1];
    float dz = pos[3 * i + 2] - pos[3 * j + 2];
    float d = sqrtf(dx * dx + dy * dy + dz * dz);
    float t = fminf(d, DMAXF) * INV_STEP;
    unsigned int b = (unsigned int)(t + 0.5f);   // nearest bin, 0..4096
    int p;
    if (b == BINS) p = atomicAdd(&curF[i], 1);          // clamped: front
    else           p = atomicSub(&curB[i], 1) - 1;      // near: back
    epk[p] = (unsigned int)j | (b << 17);
}

// fused: degree count (blocks [0,A)) + h fp16 init (blocks [A, A+B))
__global__ void k_counthinit(const int* __restrict__ ei, int* __restrict__ counts, int E_,
                             const int* __restrict__ z, const float* __restrict__ embed,
                             _Float16* __restrict__ h, int total4, int A) {
    if ((int)blockIdx.x < A) {
        int e = blockIdx.x * blockDim.x + threadIdx.x;
        if (e < E_) atomicAdd(&counts[ei[e]], 1);
    } else {
        int idx = (blockIdx.x - A) * blockDim.x + threadIdx.x;
        if (idx >= total4) return;
        int node = idx >> 5, q = idx & 31;
        float4 v = ((const float4*)embed)[(size_t)z[node] * 32 + q];
        half4v o;
        o[0] = (_Float16)v.x; o[1] = (_Float16)v.y;
        o[2] = (_Float16)v.z; o[3] = (_Float16)v.w;
        *(half4v*)(h + (size_t)node * HID + q * 4) = o;
    }
}

// all weight packs in one launch. y: 0..5 uw1 | 6..11 uw2 | 12..17 fw2->w2tf
// | 18 ow1 | 19 ow2 | 20..25 fw1->w1tf (32x128, blocks x<8 active)
__global__ void k_packall(const float* __restrict__ uw1, const float* __restrict__ uw2,
                          const float* __restrict__ fw2, const float* __restrict__ ow1,
                          const float* __restrict__ ow2, const float* __restrict__ fw1,
                          _Float16* __restrict__ uw1b, _Float16* __restrict__ uw2b,
                          _Float16* __restrict__ w2tf, _Float16* __restrict__ ow1b,
                          _Float16* __restrict__ ow2b, _Float16* __restrict__ w1tf) {
    int y = blockIdx.y;
    int lane = threadIdx.x;
    int m = lane & 15, g = lane >> 4;
    if (y < 20) {
        const float* src;
        _Float16* dst;
        if (y < 6)       { src = uw1 + (size_t)y * 16384;        dst = uw1b + (size_t)y * 16384; }
        else if (y < 12) { src = uw2 + (size_t)(y - 6) * 16384;  dst = uw2b + (size_t)(y - 6) * 16384; }
        else if (y < 18) { src = fw2 + (size_t)(y - 12) * 16384; dst = w2tf + (size_t)(y - 12) * 16384; }
        else if (y == 18){ src = ow1;                            dst = ow1b; }
        else             { src = ow2;                            dst = ow2b; }
        int b = blockIdx.x;               // kt*8+nt
        int kt = b >> 3, nt = b & 7;
        _Float16* d = dst + ((size_t)b * 64 + lane) * 8;
#pragma unroll
        for (int j = 0; j < 8; ++j)
            d[j] = (_Float16)src[(32 * kt + 8 * g + j) * 128 + 16 * nt + m];
    } else {
        int l = y - 20;
        int nt = blockIdx.x;
        if (nt >= 8) return;
        const float* src = fw1 + (size_t)l * RBF * HID;
        _Float16* d = w1tf + (size_t)l * RBF * HID + ((size_t)nt * 64 + lane) * 8;
#pragma unroll
        for (int j = 0; j < 8; ++j)
            d[j] = (_Float16)src[(8 * g + j) * 128 + 16 * nt + m];
    }
}

// 64-row GEMM helper (table build): acc += A(64x128 LDS) @ Wf
__device__ __forceinline__ void gemm64(const _Float16 (*A)[136], const _Float16* __restrict__ Wf,
                                       int lane, int c0, f32x4 acc[4][2]) {
    const int m = lane & 15, g = lane >> 4;
#pragma unroll
    for (int kt = 0; kt < 4; ++kt) {
        half8v a[4];
#pragma unroll
        for (int rt = 0; rt < 4; ++rt)
            a[rt] = *(const half8v*)&A[16 * rt + m][kt * 32 + g * 8];
#pragma unroll
        for (int t = 0; t < 2; ++t) {
            int nt = (c0 >> 4) + t;
            half8v b = *(const half8v*)(Wf + (((size_t)kt * 8 + nt) * 64 + lane) * 8);
#pragma unroll
            for (int rt = 0; rt < 4; ++rt)
                acc[rt][t] = __builtin_amdgcn_mfma_f32_16x16x32_f16(a[rt], b, acc[rt][t], 0, 0, 0);
        }
    }
}

// 32-row GEMM helper (layer kernel): acc += A(32x128 LDS) @ Wf
__device__ __forceinline__ void gemm32(const _Float16 (*A)[136], const _Float16* __restrict__ Wf,
                                       int lane, int c0, f32x4 acc[2][2]) {
    const int m = lane & 15, g = lane >> 4;
#pragma unroll
    for (int kt = 0; kt < 4; ++kt) {
        half8v a[2];
#pragma unroll
        for (int rt = 0; rt < 2; ++rt)
            a[rt] = *(const half8v*)&A[16 * rt + m][kt * 32 + g * 8];
#pragma unroll
        for (int t = 0; t < 2; ++t) {
            int nt = (c0 >> 4) + t;
            half8v b = *(const half8v*)(Wf + (((size_t)kt * 8 + nt) * 64 + lane) * 8);
#pragma unroll
            for (int rt = 0; rt < 2; ++rt)
                acc[rt][t] = __builtin_amdgcn_mfma_f32_16x16x32_f16(a[rt], b, acc[rt][t], 0, 0, 0);
        }
    }
}

template <bool SSP>
__device__ __forceinline__ void epi64(_Float16 (*dst)[136], const float* __restrict__ bias,
                                      int lane, int c0, const f32x4 acc[4][2]) {
    const int m = lane & 15, g = lane >> 4;
    float bc0 = bias[c0 + m], bc1 = bias[c0 + 16 + m];
#pragma unroll
    for (int rt = 0; rt < 4; ++rt)
#pragma unroll
        for (int t = 0; t < 2; ++t) {
            int col = c0 + 16 * t + m;
            float bc = t ? bc1 : bc0;
#pragma unroll
            for (int reg = 0; reg < 4; ++reg) {
                float v = acc[rt][t][reg] + bc;
                dst[16 * rt + 4 * g + reg][col] = (_Float16)(SSP ? sspf(v) : v);
            }
        }
}

template <bool SSP>
__device__ __forceinline__ void epi32(_Float16 (*dst)[136], const float* __restrict__ bias,
                                      int lane, int c0, const f32x4 acc[2][2]) {
    const int m = lane & 15, g = lane >> 4;
    float bc0 = bias[c0 + m], bc1 = bias[c0 + 16 + m];
#pragma unroll
    for (int rt = 0; rt < 2; ++rt)
#pragma unroll
        for (int t = 0; t < 2; ++t) {
            int col = c0 + 16 * t + m;
            float bc = t ? bc1 : bc0;
#pragma unroll
            for (int reg = 0; reg < 4; ++reg) {
                float v = acc[rt][t][reg] + bc;
                dst[16 * rt + 4 * g + reg][col] = (_Float16)(SSP ? sspf(v) : v);
            }
        }
}

// ---------- MFMA table build (64-bin tiles) ----------
__global__ __launch_bounds__(256) void k_tabmm(const _Float16* __restrict__ w1f,
                                               const float* __restrict__ fb1,
                                               const _Float16* __restrict__ w2f,
                                               const float* __restrict__ fb2,
                                               _Float16* __restrict__ tables) {
    __shared__ _Float16 R[64][40];
    __shared__ _Float16 T[64][136];
    const int tid = threadIdx.x;
    const int wave = tid >> 6, lane = tid & 63;
    const int m = lane & 15, g = lane >> 4;
    const int l = blockIdx.y;
    const int bin0 = blockIdx.x * 64;
    const int c0 = wave * 32;

    {
        int r = tid >> 2, cc0 = (tid & 3) * 8;
        float d = (float)(bin0 + r) * (DMAXF / (float)BINS);
#pragma unroll
        for (int j = 0; j < 8; ++j) {
            float dd = d - (float)(cc0 + j) * CSPACE;
            R[r][cc0 + j] = (_Float16)__expf(-GAMMAF * dd * dd);
        }
    }
    __syncthreads();

    f32x4 acc[4][2];
#pragma unroll
    for (int rt = 0; rt < 4; ++rt)
#pragma unroll
        for (int t = 0; t < 2; ++t) acc[rt][t] = (f32x4){0.f, 0.f, 0.f, 0.f};
    {
        half8v a[4];
#pragma unroll
        for (int rt = 0; rt < 4; ++rt)
            a[rt] = *(const half8v*)&R[16 * rt + m][g * 8];
#pragma unroll
        for (int t = 0; t < 2; ++t) {
            int nt = (c0 >> 4) + t;
            half8v b = *(const half8v*)(w1f + (size_t)l * RBF * HID + ((size_t)nt * 64 + lane) * 8);
#pragma unroll
            for (int rt = 0; rt < 4; ++rt)
                acc[rt][t] = __builtin_amdgcn_mfma_f32_16x16x32_f16(a[rt], b, acc[rt][t], 0, 0, 0);
        }
    }
    epi64<true>(T, fb1 + l * HID, lane, c0, acc);
    __syncthreads();

#pragma unroll
    for (int rt = 0; rt < 4; ++rt)
#pragma unroll
        for (int t = 0; t < 2; ++t) acc[rt][t] = (f32x4){0.f, 0.f, 0.f, 0.f};
    gemm64(T, w2f + (size_t)l * 16384, lane, c0, acc);
    __syncthreads();
    epi64<false>(T, fb2 + l * HID, lane, c0, acc);
    __syncthreads();
    _Float16* dst = tables + (size_t)l * (BINS + 1) * HID;
    for (int it = tid; it < 1024; it += 256) {
        int row = it >> 4, cc = (it & 15) * 8;
        int bin = bin0 + row;
        if (bin <= BINS)
            *(half8v*)(dst + (size_t)bin * HID + cc) = *(const half8v*)&T[row][cc];
    }
}

// ---------- fused layer: fp16 edge-gather + 2-GEMM MLP, 32-row tiles ----------
template <int FINAL>
__global__ __launch_bounds__(256) void k_layer(
        const int* __restrict__ row_ofs, const unsigned int* __restrict__ epk,
        const _Float16* __restrict__ h, const _Float16* __restrict__ table,
        const float* __restrict__ invdeg,
        const _Float16* __restrict__ W1f, const float* __restrict__ b1,
        const _Float16* __restrict__ W2f, const float* __restrict__ b2,
        _Float16* __restrict__ Y,
        const _Float16* __restrict__ OW1f, const float* __restrict__ ob1,
        const _Float16* __restrict__ OW2f, const float* __restrict__ ob2,
        const float* __restrict__ ow3, const float* __restrict__ ob3,
        const int* __restrict__ batch, float* __restrict__ out, int n) {
    __shared__ _Float16 U[TM][136];
    __shared__ _Float16 T[TM][136];
    const int tid = threadIdx.x;
    const int wave = tid >> 6, lane = tid & 63;
    const int quarter = lane >> 4, sub = lane & 15;
    const int row0 = blockIdx.x * TM;
    const int c0 = wave * 32;

    // ---- edge phase: quad-stream — a quarter's typical 4 edges all in flight ----
    const _Float16* hB = h + 8 * sub;
    const _Float16* tB = table + 8 * sub;
    for (int idx = 0; idx < TM / 4; ++idx) {
        int r = (TM / 4) * wave + idx;
        int node = row0 + r;
        int beg = 0, end = 0;
        if (node < n) { beg = row_ofs[node]; end = row_ofs[node + 1]; }
        half8v accA, accB;
#pragma unroll
        for (int q = 0; q < 8; ++q) { accA[q] = (_Float16)0.f; accB[q] = (_Float16)0.f; }
        int k = beg + quarter;
        // quad-stream: 4 epk decodes + 4 h loads + 4 tw loads issued before any FMA
        while (k + 12 < end) {
            unsigned int pk0 = epk[k];
            unsigned int pk1 = epk[k + 4];
            unsigned int pk2 = epk[k + 8];
            unsigned int pk3 = epk[k + 12];
            int j0 = pk0 & 0x1FFFF, b0 = (int)(pk0 >> 17);
            int j1 = pk1 & 0x1FFFF, b1_ = (int)(pk1 >> 17);
            int j2 = pk2 & 0x1FFFF, b2_ = (int)(pk2 >> 17);
            int j3 = pk3 & 0x1FFFF, b3 = (int)(pk3 >> 17);
            half8v hj0 = *(const half8v*)(hB + (size_t)j0 * HID);
            half8v hj1 = *(const half8v*)(hB + (size_t)j1 * HID);
            half8v hj2 = *(const half8v*)(hB + (size_t)j2 * HID);
            half8v hj3 = *(const half8v*)(hB + (size_t)j3 * HID);
            half8v tw0 = *(const half8v*)(tB + (size_t)b0 * HID);
            half8v tw1 = *(const half8v*)(tB + (size_t)b1_ * HID);
            half8v tw2 = *(const half8v*)(tB + (size_t)b2_ * HID);
            half8v tw3 = *(const half8v*)(tB + (size_t)b3 * HID);
            accA += hj0 * tw0;
            accB += hj1 * tw1;
            accA += hj2 * tw2;
            accB += hj3 * tw3;
            k += 16;
        }
        while (k < end) {
            unsigned int pk = epk[k];
            int j = pk & 0x1FFFF, b = (int)(pk >> 17);
            half8v hj = *(const half8v*)(hB + (size_t)j * HID);
            half8v tw = *(const half8v*)(tB + (size_t)b * HID);
            accA += hj * tw;
            k += 4;
        }
        accA += accB;
        int4 ai = *(int4*)&accA;
#pragma unroll
        for (int o = 32; o >= 16; o >>= 1) {
            int4 oi;
            oi.x = __shfl_xor(ai.x, o);
            oi.y = __shfl_xor(ai.y, o);
            oi.z = __shfl_xor(ai.z, o);
            oi.w = __shfl_xor(ai.w, o);
            half8v ov = *(half8v*)&oi;
            half8v av = *(half8v*)&ai;
            av += ov;
            ai = *(int4*)&av;
        }
        if (quarter == 0) {
            half8v av = *(half8v*)&ai;
            float s = (node < n) ? invdeg[node] : 0.f;
            half8v o;
#pragma unroll
            for (int q = 0; q < 8; ++q) o[q] = (_Float16)((float)av[q] * s);
            *(half8v*)&U[r][8 * sub] = o;
        }
    }
    __syncthreads();

    // ---- GEMM 1: U @ W1, ssp -> T ----
    f32x4 acc[2][2];
#pragma unroll
    for (int rt = 0; rt < 2; ++rt)
#pragma unroll
        for (int t = 0; t < 2; ++t) acc[rt][t] = (f32x4){0.f, 0.f, 0.f, 0.f};
    gemm32(U, W1f, lane, c0, acc);
    epi32<true>(T, b1, lane, c0, acc);
    __syncthreads();

    // ---- GEMM 2: T @ W2 ----
#pragma unroll
    for (int rt = 0; rt < 2; ++rt)
#pragma unroll
        for (int t = 0; t < 2; ++t) acc[rt][t] = (f32x4){0.f, 0.f, 0.f, 0.f};
    gemm32(T, W2f, lane, c0, acc);

    if (FINAL == 0) {
        epi32<false>(U, b2, lane, c0, acc);   // U dead since last sync
        __syncthreads();
        for (int it = tid; it < TM * 16; it += 256) {
            int row = it >> 4, cc = (it & 15) * 8;
            int r = row0 + row;
            if (r < n)
                *(half8v*)(Y + (size_t)r * HID + cc) = *(const half8v*)&U[row][cc];
        }
    } else {
        // h6 -> U, then output block GEMMs
        epi32<false>(U, b2, lane, c0, acc);
        __syncthreads();
#pragma unroll
        for (int rt = 0; rt < 2; ++rt)
#pragma unroll
            for (int t = 0; t < 2; ++t) acc[rt][t] = (f32x4){0.f, 0.f, 0.f, 0.f};
        gemm32(U, OW1f, lane, c0, acc);
        epi32<true>(T, ob1, lane, c0, acc);
        __syncthreads();
#pragma unroll
        for (int rt = 0; rt < 2; ++rt)
#pragma unroll
            for (int t = 0; t < 2; ++t) acc[rt][t] = (f32x4){0.f, 0.f, 0.f, 0.f};
        gemm32(T, OW2f, lane, c0, acc);
        __shared__ float ea[4][TM];
        __shared__ float ev[TM];
        __shared__ int   bv[TM];
        const int m = lane & 15, g = lane >> 4;
        float bc0 = ob2[c0 + m], bc1 = ob2[c0 + 16 + m];
        float w0 = ow3[c0 + m], w1 = ow3[c0 + 16 + m];
#pragma unroll
        for (int rt = 0; rt < 2; ++rt) {
#pragma unroll
            for (int reg = 0; reg < 4; ++reg) {
                float p = sspf(acc[rt][0][reg] + bc0) * w0
                        + sspf(acc[rt][1][reg] + bc1) * w1;
                p += __shfl_xor(p, 1);
                p += __shfl_xor(p, 2);
                p += __shfl_xor(p, 4);
                p += __shfl_xor(p, 8);
                if (m == 0) ea[wave][16 * rt + 4 * g + reg] = p;
            }
        }
        __syncthreads();
        if (tid < TM) {
            int r = tid, row = row0 + r;
            float e = ea[0][r] + ea[1][r] + ea[2][r] + ea[3][r] + ob3[0];
            int bid = (row < n) ? batch[row] : -1;
            ev[r] = (row < n) ? e : 0.f;
            bv[r] = bid;
        }
        __syncthreads();
        if (tid < TM) {
            int r = tid, bid = bv[r];
            if (bid >= 0 && (r == 0 || bv[r - 1] != bid)) {
                float s = 0.f;
                for (int k2 = r; k2 < TM && bv[k2] == bid; ++k2) s += ev[k2];
                atomicAdd(&out[bid], s);
            }
        }
    }
}

extern "C" void kernel_launch(void* const* d_in, const int* in_sizes, int n_in,
                              void* d_out, int out_size, void* d_ws, size_t ws_size,
                              hipStream_t stream) {
    const int*   z     = (const int*)d_in[0];
    const float* pos   = (const float*)d_in[1];
    const int*   ei    = (const int*)d_in[2];
    const int*   batch = (const int*)d_in[3];
    const float* embed = (const float*)d_in[4];
    const float* fw1   = (const float*)d_in[5];
    const float* fb1   = (const float*)d_in[6];
    const float* fw2   = (const float*)d_in[7];
    const float* fb2   = (const float*)d_in[8];
    const float* uw1   = (const float*)d_in[9];
    const float* ub1   = (const float*)d_in[10];
    const float* uw2   = (const float*)d_in[11];
    const float* ub2   = (const float*)d_in[12];
    const float* ow1   = (const float*)d_in[13];
    const float* ob1   = (const float*)d_in[14];
    const float* ow2   = (const float*)d_in[15];
    const float* ob2   = (const float*)d_in[16];
    const float* ow3   = (const float*)d_in[17];
    const float* ob3   = (const float*)d_in[18];

    const int N = in_sizes[0];
    const int E = in_sizes[2] / 2;
    const int NB = (N + SB - 1) / SB;

    char* p = (char*)d_ws;
    auto alloc = [&](size_t bytes) {
        char* r = p;
        p += (bytes + 255) & ~(size_t)255;
        return r;
    };
    _Float16* h       = (_Float16*)alloc((size_t)(N + TM) * HID * 2);
    _Float16* h2      = (_Float16*)alloc((size_t)(N + TM) * HID * 2);
    unsigned int* epk = (unsigned int*)alloc((size_t)E * 4);
    int*      counts  = (int*)alloc((size_t)N * 4);
    int*      row_ofs = (int*)alloc((size_t)(N + 1) * 4);
    int*      curF    = (int*)alloc((size_t)N * 4);
    int*      curB    = (int*)alloc((size_t)N * 4);
    int*      pre     = (int*)alloc((size_t)N * 4);
    int*      bsums   = (int*)alloc((size_t)1024 * 4);
    float*    invdeg  = (float*)alloc((size_t)N * 4);
    _Float16* tab16   = (_Float16*)alloc((size_t)NL * (BINS + 1) * HID * 2);
    _Float16* w1tf    = (_Float16*)alloc((size_t)NL * RBF * HID * 2);
    _Float16* w2tf    = (_Float16*)alloc((size_t)NL * 16384 * 2);
    _Float16* uw1b    = (_Float16*)alloc((size_t)NL * 16384 * 2);
    _Float16* uw2b    = (_Float16*)alloc((size_t)NL * 16384 * 2);
    _Float16* ow1b    = (_Float16*)alloc((size_t)16384 * 2);
    _Float16* ow2b    = (_Float16*)alloc((size_t)16384 * 2);

    const int TB = 256;
    hipMemsetAsync(counts, 0, (size_t)N * 4, stream);
    hipMemsetAsync(d_out, 0, (size_t)out_size * sizeof(float), stream);

    int tot4 = N * 32;
    int A = (E + TB - 1) / TB;
    int B = (tot4 + TB - 1) / TB;
    k_counthinit<<<A + B, TB, 0, stream>>>(ei, counts, E, z, embed, h, tot4, A);
    k_packall<<<dim3(32, 26), 64, 0, stream>>>(uw1, uw2, fw2, ow1, ow2, fw1,
                                               uw1b, uw2b, w2tf, ow1b, ow2b, w1tf);
    k_scan1<<<NB, SB, 0, stream>>>(counts, pre, bsums, N);
    k_scan2<<<1, 1024, 0, stream>>>(bsums, NB);
    k_scan3<<<NB, SB, 0, stream>>>(pre, bsums, counts, row_ofs, curF, curB, invdeg, N);
    k_scatter<<<A, TB, 0, stream>>>(ei, pos, curF, curB, epk, E);
    k_tabmm<<<dim3((BINS + 1 + 63) / 64, NL), 256, 0, stream>>>(w1tf, fb1, w2tf, fb2, tab16);

    int mblocks = (N + TM - 1) / TM;

    _Float16* cur = h;
    _Float16* nxt = h2;
    for (int l = 0; l < NL - 1; ++l) {
        k_layer<0><<<mblocks, TB, 0, stream>>>(row_ofs, epk, cur,
                                               tab16 + (size_t)l * (BINS + 1) * HID, invdeg,
                                               uw1b + (size_t)l * 16384, ub1 + (size_t)l * HID,
                                               uw2b + (size_t)l * 16384, ub2 + (size_t)l * HID,
                                               nxt,
                                               nullptr, nullptr, nullptr, nullptr,
                                               nullptr, nullptr, nullptr, nullptr, N);
        _Float16* tmp = cur; cur = nxt; nxt = tmp;
    }
    k_layer<1><<<mblocks, TB, 0, stream>>>(row_ofs, epk, cur,
                                           tab16 + (size_t)(NL - 1) * (BINS + 1) * HID, invdeg,
                                           uw1b + (size_t)(NL - 1) * 16384, ub1 + (size_t)(NL - 1) * HID,
                                           uw2b + (size_t)(NL - 1) * 16384, ub2 + (size_t)(NL - 1) * HID,
                                           nullptr,
                                           ow1b, ob1, ow2b, ob2,
                                           ow3, ob3, batch, (float*)d_out, N);
}

// Round 17
// 440.408 us; speedup vs baseline: 1.2521x; 1.2521x over previous
//
#include <hip/hip_runtime.h>
#include <math.h>

#define HID 128
#define RBF 32
#define NL 6
#define BINS 4096
#define DMAXF 5.0f
#define INV_STEP (4096.0f / 5.0f)
#define GAMMAF 32.0f
#define CSPACE (4.0f / 31.0f)   // linspace(0,4,32) spacing
#define TM 32                   // rows per block

typedef _Float16 half8v __attribute__((ext_vector_type(8)));
typedef _Float16 half4v __attribute__((ext_vector_type(4)));
typedef float f32x4 __attribute__((ext_vector_type(4)));

// softplus(x)-0.5 via HW transcendentals (v_exp_f32/v_log_f32)
__device__ __forceinline__ float sspf(float x) {
    return fmaxf(x, 0.0f) + __logf(1.0f + __expf(-fabsf(x))) - 0.5f;
}

// ---------- one-time preprocessing ----------

#define SB 256
__global__ void k_scan1(const int* __restrict__ counts, int* __restrict__ pre,
                        int* __restrict__ bsums, int n) {
    __shared__ int s[SB];
    int tid = threadIdx.x;
    int g = blockIdx.x * SB + tid;
    int v = (g < n) ? counts[g] : 0;
    s[tid] = v;
    __syncthreads();
    for (int off = 1; off < SB; off <<= 1) {
        int t = (tid >= off) ? s[tid - off] : 0;
        __syncthreads();
        s[tid] += t;
        __syncthreads();
    }
    if (g < n) pre[g] = s[tid] - v;
    if (tid == SB - 1) bsums[blockIdx.x] = s[tid];
}

__global__ void k_scan2(int* __restrict__ bsums, int nb) {
    __shared__ int s[1024];
    int tid = threadIdx.x;
    int v = (tid < nb) ? bsums[tid] : 0;
    s[tid] = v;
    __syncthreads();
    for (int off = 1; off < 1024; off <<= 1) {
        int t = (tid >= off) ? s[tid - off] : 0;
        __syncthreads();
        s[tid] += t;
        __syncthreads();
    }
    if (tid < nb) bsums[tid] = s[tid] - v;
}

// exclusive-scan apply + front/back cursors (clamped edges fill from front,
// near edges from back -> runs of same type per CSR segment)
__global__ void k_scan3(const int* __restrict__ pre, const int* __restrict__ bsums,
                        const int* __restrict__ counts, int* __restrict__ row_ofs,
                        int* __restrict__ curF, int* __restrict__ curB,
                        float* __restrict__ invdeg, int n) {
    int g = blockIdx.x * SB + threadIdx.x;
    if (g >= n) return;
    int r = pre[g] + bsums[g >> 8];
    row_ofs[g] = r;
    curF[g] = r;
    curB[g] = r + counts[g];
    invdeg[g] = 1.0f / fmaxf((float)counts[g], 1.0f);
    if (g == n - 1) row_ofs[n] = r + counts[g];
}

__global__ void k_scatter(const int* __restrict__ ei, const float* __restrict__ pos,
                          int* __restrict__ curF, int* __restrict__ curB,
                          unsigned int* __restrict__ epk, int E_) {
    int e = blockIdx.x * blockDim.x + threadIdx.x;
    if (e >= E_) return;
    int i = ei[e], j = ei[E_ + e];
    float dx = pos[3 * i]     - pos[3 * j];
    float dy = pos[3 * i + 1] - pos[3 * j + 1];
    float dz = pos[3 * i + 2] - pos[3 * j + 2];
    float d = sqrtf(dx * dx + dy * dy + dz * dz);
    float t = fminf(d, DMAXF) * INV_STEP;
    unsigned int b = (unsigned int)(t + 0.5f);   // nearest bin, 0..4096
    int p;
    if (b == BINS) p = atomicAdd(&curF[i], 1);          // clamped: front
    else           p = atomicSub(&curB[i], 1) - 1;      // near: back
    epk[p] = (unsigned int)j | (b << 17);
}

// fused: degree count (blocks [0,A)) + h fp16 init (blocks [A, A+B))
__global__ void k_counthinit(const int* __restrict__ ei, int* __restrict__ counts, int E_,
                             const int* __restrict__ z, const float* __restrict__ embed,
                             _Float16* __restrict__ h, int total4, int A) {
    if ((int)blockIdx.x < A) {
        int e = blockIdx.x * blockDim.x + threadIdx.x;
        if (e < E_) atomicAdd(&counts[ei[e]], 1);
    } else {
        int idx = (blockIdx.x - A) * blockDim.x + threadIdx.x;
        if (idx >= total4) return;
        int node = idx >> 5, q = idx & 31;
        float4 v = ((const float4*)embed)[(size_t)z[node] * 32 + q];
        half4v o;
        o[0] = (_Float16)v.x; o[1] = (_Float16)v.y;
        o[2] = (_Float16)v.z; o[3] = (_Float16)v.w;
        *(half4v*)(h + (size_t)node * HID + q * 4) = o;
    }
}

// all weight packs in one launch. y: 0..5 uw1 | 6..11 uw2 | 12..17 fw2->w2tf
// | 18 ow1 | 19 ow2 | 20..25 fw1->w1tf (32x128, blocks x<8 active)
__global__ void k_packall(const float* __restrict__ uw1, const float* __restrict__ uw2,
                          const float* __restrict__ fw2, const float* __restrict__ ow1,
                          const float* __restrict__ ow2, const float* __restrict__ fw1,
                          _Float16* __restrict__ uw1b, _Float16* __restrict__ uw2b,
                          _Float16* __restrict__ w2tf, _Float16* __restrict__ ow1b,
                          _Float16* __restrict__ ow2b, _Float16* __restrict__ w1tf) {
    int y = blockIdx.y;
    int lane = threadIdx.x;
    int m = lane & 15, g = lane >> 4;
    if (y < 20) {
        const float* src;
        _Float16* dst;
        if (y < 6)       { src = uw1 + (size_t)y * 16384;        dst = uw1b + (size_t)y * 16384; }
        else if (y < 12) { src = uw2 + (size_t)(y - 6) * 16384;  dst = uw2b + (size_t)(y - 6) * 16384; }
        else if (y < 18) { src = fw2 + (size_t)(y - 12) * 16384; dst = w2tf + (size_t)(y - 12) * 16384; }
        else if (y == 18){ src = ow1;                            dst = ow1b; }
        else             { src = ow2;                            dst = ow2b; }
        int b = blockIdx.x;               // kt*8+nt
        int kt = b >> 3, nt = b & 7;
        _Float16* d = dst + ((size_t)b * 64 + lane) * 8;
#pragma unroll
        for (int j = 0; j < 8; ++j)
            d[j] = (_Float16)src[(32 * kt + 8 * g + j) * 128 + 16 * nt + m];
    } else {
        int l = y - 20;
        int nt = blockIdx.x;
        if (nt >= 8) return;
        const float* src = fw1 + (size_t)l * RBF * HID;
        _Float16* d = w1tf + (size_t)l * RBF * HID + ((size_t)nt * 64 + lane) * 8;
#pragma unroll
        for (int j = 0; j < 8; ++j)
            d[j] = (_Float16)src[(8 * g + j) * 128 + 16 * nt + m];
    }
}

// 64-row GEMM helper (table build): acc += A(64x128 LDS) @ Wf
__device__ __forceinline__ void gemm64(const _Float16 (*A)[136], const _Float16* __restrict__ Wf,
                                       int lane, int c0, f32x4 acc[4][2]) {
    const int m = lane & 15, g = lane >> 4;
#pragma unroll
    for (int kt = 0; kt < 4; ++kt) {
        half8v a[4];
#pragma unroll
        for (int rt = 0; rt < 4; ++rt)
            a[rt] = *(const half8v*)&A[16 * rt + m][kt * 32 + g * 8];
#pragma unroll
        for (int t = 0; t < 2; ++t) {
            int nt = (c0 >> 4) + t;
            half8v b = *(const half8v*)(Wf + (((size_t)kt * 8 + nt) * 64 + lane) * 8);
#pragma unroll
            for (int rt = 0; rt < 4; ++rt)
                acc[rt][t] = __builtin_amdgcn_mfma_f32_16x16x32_f16(a[rt], b, acc[rt][t], 0, 0, 0);
        }
    }
}

// 32-row GEMM helper (layer kernel): acc += A(32x128 LDS) @ Wf
__device__ __forceinline__ void gemm32(const _Float16 (*A)[136], const _Float16* __restrict__ Wf,
                                       int lane, int c0, f32x4 acc[2][2]) {
    const int m = lane & 15, g = lane >> 4;
#pragma unroll
    for (int kt = 0; kt < 4; ++kt) {
        half8v a[2];
#pragma unroll
        for (int rt = 0; rt < 2; ++rt)
            a[rt] = *(const half8v*)&A[16 * rt + m][kt * 32 + g * 8];
#pragma unroll
        for (int t = 0; t < 2; ++t) {
            int nt = (c0 >> 4) + t;
            half8v b = *(const half8v*)(Wf + (((size_t)kt * 8 + nt) * 64 + lane) * 8);
#pragma unroll
            for (int rt = 0; rt < 2; ++rt)
                acc[rt][t] = __builtin_amdgcn_mfma_f32_16x16x32_f16(a[rt], b, acc[rt][t], 0, 0, 0);
        }
    }
}

template <bool SSP>
__device__ __forceinline__ void epi64(_Float16 (*dst)[136], const float* __restrict__ bias,
                                      int lane, int c0, const f32x4 acc[4][2]) {
    const int m = lane & 15, g = lane >> 4;
    float bc0 = bias[c0 + m], bc1 = bias[c0 + 16 + m];
#pragma unroll
    for (int rt = 0; rt < 4; ++rt)
#pragma unroll
        for (int t = 0; t < 2; ++t) {
            int col = c0 + 16 * t + m;
            float bc = t ? bc1 : bc0;
#pragma unroll
            for (int reg = 0; reg < 4; ++reg) {
                float v = acc[rt][t][reg] + bc;
                dst[16 * rt + 4 * g + reg][col] = (_Float16)(SSP ? sspf(v) : v);
            }
        }
}

template <bool SSP>
__device__ __forceinline__ void epi32(_Float16 (*dst)[136], const float* __restrict__ bias,
                                      int lane, int c0, const f32x4 acc[2][2]) {
    const int m = lane & 15, g = lane >> 4;
    float bc0 = bias[c0 + m], bc1 = bias[c0 + 16 + m];
#pragma unroll
    for (int rt = 0; rt < 2; ++rt)
#pragma unroll
        for (int t = 0; t < 2; ++t) {
            int col = c0 + 16 * t + m;
            float bc = t ? bc1 : bc0;
#pragma unroll
            for (int reg = 0; reg < 4; ++reg) {
                float v = acc[rt][t][reg] + bc;
                dst[16 * rt + 4 * g + reg][col] = (_Float16)(SSP ? sspf(v) : v);
            }
        }
}

// ---------- MFMA table build (64-bin tiles) ----------
__global__ __launch_bounds__(256) void k_tabmm(const _Float16* __restrict__ w1f,
                                               const float* __restrict__ fb1,
                                               const _Float16* __restrict__ w2f,
                                               const float* __restrict__ fb2,
                                               _Float16* __restrict__ tables) {
    __shared__ _Float16 R[64][40];
    __shared__ _Float16 T[64][136];
    const int tid = threadIdx.x;
    const int wave = tid >> 6, lane = tid & 63;
    const int m = lane & 15, g = lane >> 4;
    const int l = blockIdx.y;
    const int bin0 = blockIdx.x * 64;
    const int c0 = wave * 32;

    {
        int r = tid >> 2, cc0 = (tid & 3) * 8;
        float d = (float)(bin0 + r) * (DMAXF / (float)BINS);
#pragma unroll
        for (int j = 0; j < 8; ++j) {
            float dd = d - (float)(cc0 + j) * CSPACE;
            R[r][cc0 + j] = (_Float16)__expf(-GAMMAF * dd * dd);
        }
    }
    __syncthreads();

    f32x4 acc[4][2];
#pragma unroll
    for (int rt = 0; rt < 4; ++rt)
#pragma unroll
        for (int t = 0; t < 2; ++t) acc[rt][t] = (f32x4){0.f, 0.f, 0.f, 0.f};
    {
        half8v a[4];
#pragma unroll
        for (int rt = 0; rt < 4; ++rt)
            a[rt] = *(const half8v*)&R[16 * rt + m][g * 8];
#pragma unroll
        for (int t = 0; t < 2; ++t) {
            int nt = (c0 >> 4) + t;
            half8v b = *(const half8v*)(w1f + (size_t)l * RBF * HID + ((size_t)nt * 64 + lane) * 8);
#pragma unroll
            for (int rt = 0; rt < 4; ++rt)
                acc[rt][t] = __builtin_amdgcn_mfma_f32_16x16x32_f16(a[rt], b, acc[rt][t], 0, 0, 0);
        }
    }
    epi64<true>(T, fb1 + l * HID, lane, c0, acc);
    __syncthreads();

#pragma unroll
    for (int rt = 0; rt < 4; ++rt)
#pragma unroll
        for (int t = 0; t < 2; ++t) acc[rt][t] = (f32x4){0.f, 0.f, 0.f, 0.f};
    gemm64(T, w2f + (size_t)l * 16384, lane, c0, acc);
    __syncthreads();
    epi64<false>(T, fb2 + l * HID, lane, c0, acc);
    __syncthreads();
    _Float16* dst = tables + (size_t)l * (BINS + 1) * HID;
    for (int it = tid; it < 1024; it += 256) {
        int row = it >> 4, cc = (it & 15) * 8;
        int bin = bin0 + row;
        if (bin <= BINS)
            *(half8v*)(dst + (size_t)bin * HID + cc) = *(const half8v*)&T[row][cc];
    }
}

// ---------- fused layer: fp16 edge-gather + 2-GEMM MLP, 32-row tiles ----------
template <int FINAL>
__global__ __launch_bounds__(256) void k_layer(
        const int* __restrict__ row_ofs, const unsigned int* __restrict__ epk,
        const _Float16* __restrict__ h, const _Float16* __restrict__ table,
        const float* __restrict__ invdeg,
        const _Float16* __restrict__ W1f, const float* __restrict__ b1,
        const _Float16* __restrict__ W2f, const float* __restrict__ b2,
        _Float16* __restrict__ Y,
        const _Float16* __restrict__ OW1f, const float* __restrict__ ob1,
        const _Float16* __restrict__ OW2f, const float* __restrict__ ob2,
        const float* __restrict__ ow3, const float* __restrict__ ob3,
        const int* __restrict__ batch, float* __restrict__ out, int n) {
    __shared__ _Float16 U[TM][136];
    __shared__ _Float16 T[TM][136];
    const int tid = threadIdx.x;
    const int wave = tid >> 6, lane = tid & 63;
    const int quarter = lane >> 4, sub = lane & 15;
    const int row0 = blockIdx.x * TM;
    const int c0 = wave * 32;

    // ---- edge phase: 4 quarters x 2 streams; branchless tw loads (b<=BINS always valid) ----
    const _Float16* hB = h + 8 * sub;
    const _Float16* tB = table + 8 * sub;
    for (int idx = 0; idx < TM / 4; ++idx) {
        int r = (TM / 4) * wave + idx;
        int node = row0 + r;
        int beg = 0, end = 0;
        if (node < n) { beg = row_ofs[node]; end = row_ofs[node + 1]; }
        half8v accA, accB;
#pragma unroll
        for (int q = 0; q < 8; ++q) { accA[q] = (_Float16)0.f; accB[q] = (_Float16)0.f; }
        int k = beg + quarter;
        // dual-stream, straight-line: 4 independent VMEM loads before either FMA
        while (k + 4 < end) {
            unsigned int pkA = epk[k];
            unsigned int pkB = epk[k + 4];
            int jA = pkA & 0x1FFFF, bA = (int)(pkA >> 17);
            int jB = pkB & 0x1FFFF, bB = (int)(pkB >> 17);
            half8v hjA = *(const half8v*)(hB + (size_t)jA * HID);
            half8v hjB = *(const half8v*)(hB + (size_t)jB * HID);
            half8v twA = *(const half8v*)(tB + (size_t)bA * HID);  // clamp row L1-hit for ~74%
            half8v twB = *(const half8v*)(tB + (size_t)bB * HID);
            accA += hjA * twA;
            accB += hjB * twB;
            k += 8;
        }
        if (k < end) {
            unsigned int pk = epk[k];
            int j = pk & 0x1FFFF, b = (int)(pk >> 17);
            half8v hj = *(const half8v*)(hB + (size_t)j * HID);
            half8v tw = *(const half8v*)(tB + (size_t)b * HID);
            accA += hj * tw;
        }
        accA += accB;
        int4 ai = *(int4*)&accA;
#pragma unroll
        for (int o = 32; o >= 16; o >>= 1) {
            int4 oi;
            oi.x = __shfl_xor(ai.x, o);
            oi.y = __shfl_xor(ai.y, o);
            oi.z = __shfl_xor(ai.z, o);
            oi.w = __shfl_xor(ai.w, o);
            half8v ov = *(half8v*)&oi;
            half8v av = *(half8v*)&ai;
            av += ov;
            ai = *(int4*)&av;
        }
        if (quarter == 0) {
            half8v av = *(half8v*)&ai;
            float s = (node < n) ? invdeg[node] : 0.f;
            half8v o;
#pragma unroll
            for (int q = 0; q < 8; ++q) o[q] = (_Float16)((float)av[q] * s);
            *(half8v*)&U[r][8 * sub] = o;
        }
    }
    __syncthreads();

    // ---- GEMM 1: U @ W1, ssp -> T ----
    f32x4 acc[2][2];
#pragma unroll
    for (int rt = 0; rt < 2; ++rt)
#pragma unroll
        for (int t = 0; t < 2; ++t) acc[rt][t] = (f32x4){0.f, 0.f, 0.f, 0.f};
    gemm32(U, W1f, lane, c0, acc);
    epi32<true>(T, b1, lane, c0, acc);
    __syncthreads();

    // ---- GEMM 2: T @ W2 ----
#pragma unroll
    for (int rt = 0; rt < 2; ++rt)
#pragma unroll
        for (int t = 0; t < 2; ++t) acc[rt][t] = (f32x4){0.f, 0.f, 0.f, 0.f};
    gemm32(T, W2f, lane, c0, acc);

    if (FINAL == 0) {
        epi32<false>(U, b2, lane, c0, acc);   // U dead since last sync
        __syncthreads();
        for (int it = tid; it < TM * 16; it += 256) {
            int row = it >> 4, cc = (it & 15) * 8;
            int r = row0 + row;
            if (r < n)
                *(half8v*)(Y + (size_t)r * HID + cc) = *(const half8v*)&U[row][cc];
        }
    } else {
        // h6 -> U, then output block GEMMs
        epi32<false>(U, b2, lane, c0, acc);
        __syncthreads();
#pragma unroll
        for (int rt = 0; rt < 2; ++rt)
#pragma unroll
            for (int t = 0; t < 2; ++t) acc[rt][t] = (f32x4){0.f, 0.f, 0.f, 0.f};
        gemm32(U, OW1f, lane, c0, acc);
        epi32<true>(T, ob1, lane, c0, acc);
        __syncthreads();
#pragma unroll
        for (int rt = 0; rt < 2; ++rt)
#pragma unroll
            for (int t = 0; t < 2; ++t) acc[rt][t] = (f32x4){0.f, 0.f, 0.f, 0.f};
        gemm32(T, OW2f, lane, c0, acc);
        __shared__ float ea[4][TM];
        __shared__ float ev[TM];
        __shared__ int   bv[TM];
        const int m = lane & 15, g = lane >> 4;
        float bc0 = ob2[c0 + m], bc1 = ob2[c0 + 16 + m];
        float w0 = ow3[c0 + m], w1 = ow3[c0 + 16 + m];
#pragma unroll
        for (int rt = 0; rt < 2; ++rt) {
#pragma unroll
            for (int reg = 0; reg < 4; ++reg) {
                float p = sspf(acc[rt][0][reg] + bc0) * w0
                        + sspf(acc[rt][1][reg] + bc1) * w1;
                p += __shfl_xor(p, 1);
                p += __shfl_xor(p, 2);
                p += __shfl_xor(p, 4);
                p += __shfl_xor(p, 8);
                if (m == 0) ea[wave][16 * rt + 4 * g + reg] = p;
            }
        }
        __syncthreads();
        if (tid < TM) {
            int r = tid, row = row0 + r;
            float e = ea[0][r] + ea[1][r] + ea[2][r] + ea[3][r] + ob3[0];
            int bid = (row < n) ? batch[row] : -1;
            ev[r] = (row < n) ? e : 0.f;
            bv[r] = bid;
        }
        __syncthreads();
        if (tid < TM) {
            int r = tid, bid = bv[r];
            if (bid >= 0 && (r == 0 || bv[r - 1] != bid)) {
                float s = 0.f;
                for (int k2 = r; k2 < TM && bv[k2] == bid; ++k2) s += ev[k2];
                atomicAdd(&out[bid], s);
            }
        }
    }
}

extern "C" void kernel_launch(void* const* d_in, const int* in_sizes, int n_in,
                              void* d_out, int out_size, void* d_ws, size_t ws_size,
                              hipStream_t stream) {
    const int*   z     = (const int*)d_in[0];
    const float* pos   = (const float*)d_in[1];
    const int*   ei    = (const int*)d_in[2];
    const int*   batch = (const int*)d_in[3];
    const float* embed = (const float*)d_in[4];
    const float* fw1   = (const float*)d_in[5];
    const float* fb1   = (const float*)d_in[6];
    const float* fw2   = (const float*)d_in[7];
    const float* fb2   = (const float*)d_in[8];
    const float* uw1   = (const float*)d_in[9];
    const float* ub1   = (const float*)d_in[10];
    const float* uw2   = (const float*)d_in[11];
    const float* ub2   = (const float*)d_in[12];
    const float* ow1   = (const float*)d_in[13];
    const float* ob1   = (const float*)d_in[14];
    const float* ow2   = (const float*)d_in[15];
    const float* ob2   = (const float*)d_in[16];
    const float* ow3   = (const float*)d_in[17];
    const float* ob3   = (const float*)d_in[18];

    const int N = in_sizes[0];
    const int E = in_sizes[2] / 2;
    const int NB = (N + SB - 1) / SB;

    char* p = (char*)d_ws;
    auto alloc = [&](size_t bytes) {
        char* r = p;
        p += (bytes + 255) & ~(size_t)255;
        return r;
    };
    _Float16* h       = (_Float16*)alloc((size_t)(N + TM) * HID * 2);
    _Float16* h2      = (_Float16*)alloc((size_t)(N + TM) * HID * 2);
    unsigned int* epk = (unsigned int*)alloc((size_t)E * 4);
    int*      counts  = (int*)alloc((size_t)N * 4);
    int*      row_ofs = (int*)alloc((size_t)(N + 1) * 4);
    int*      curF    = (int*)alloc((size_t)N * 4);
    int*      curB    = (int*)alloc((size_t)N * 4);
    int*      pre     = (int*)alloc((size_t)N * 4);
    int*      bsums   = (int*)alloc((size_t)1024 * 4);
    float*    invdeg  = (float*)alloc((size_t)N * 4);
    _Float16* tab16   = (_Float16*)alloc((size_t)NL * (BINS + 1) * HID * 2);
    _Float16* w1tf    = (_Float16*)alloc((size_t)NL * RBF * HID * 2);
    _Float16* w2tf    = (_Float16*)alloc((size_t)NL * 16384 * 2);
    _Float16* uw1b    = (_Float16*)alloc((size_t)NL * 16384 * 2);
    _Float16* uw2b    = (_Float16*)alloc((size_t)NL * 16384 * 2);
    _Float16* ow1b    = (_Float16*)alloc((size_t)16384 * 2);
    _Float16* ow2b    = (_Float16*)alloc((size_t)16384 * 2);

    const int TB = 256;
    hipMemsetAsync(counts, 0, (size_t)N * 4, stream);
    hipMemsetAsync(d_out, 0, (size_t)out_size * sizeof(float), stream);

    int tot4 = N * 32;
    int A = (E + TB - 1) / TB;
    int B = (tot4 + TB - 1) / TB;
    k_counthinit<<<A + B, TB, 0, stream>>>(ei, counts, E, z, embed, h, tot4, A);
    k_packall<<<dim3(32, 26), 64, 0, stream>>>(uw1, uw2, fw2, ow1, ow2, fw1,
                                               uw1b, uw2b, w2tf, ow1b, ow2b, w1tf);
    k_scan1<<<NB, SB, 0, stream>>>(counts, pre, bsums, N);
    k_scan2<<<1, 1024, 0, stream>>>(bsums, NB);
    k_scan3<<<NB, SB, 0, stream>>>(pre, bsums, counts, row_ofs, curF, curB, invdeg, N);
    k_scatter<<<A, TB, 0, stream>>>(ei, pos, curF, curB, epk, E);
    k_tabmm<<<dim3((BINS + 1 + 63) / 64, NL), 256, 0, stream>>>(w1tf, fb1, w2tf, fb2, tab16);

    int mblocks = (N + TM - 1) / TM;

    _Float16* cur = h;
    _Float16* nxt = h2;
    for (int l = 0; l < NL - 1; ++l) {
        k_layer<0><<<mblocks, TB, 0, stream>>>(row_ofs, epk, cur,
                                               tab16 + (size_t)l * (BINS + 1) * HID, invdeg,
                                               uw1b + (size_t)l * 16384, ub1 + (size_t)l * HID,
                                               uw2b + (size_t)l * 16384, ub2 + (size_t)l * HID,
                                               nxt,
                                               nullptr, nullptr, nullptr, nullptr,
                                               nullptr, nullptr, nullptr, nullptr, N);
        _Float16* tmp = cur; cur = nxt; nxt = tmp;
    }
    k_layer<1><<<mblocks, TB, 0, stream>>>(row_ofs, epk, cur,
                                           tab16 + (size_t)(NL - 1) * (BINS + 1) * HID, invdeg,
                                           uw1b + (size_t)(NL - 1) * 16384, ub1 + (size_t)(NL - 1) * HID,
                                           uw2b + (size_t)(NL - 1) * 16384, ub2 + (size_t)(NL - 1) * HID,
                                           nullptr,
                                           ow1b, ob1, ow2b, ob2,
                                           ow3, ob3, batch, (float*)d_out, N);
}